// Round 1
// baseline (182.595 us; speedup 1.0000x reference)
//
#include <hip/hip_runtime.h>
#include <math.h>

// Problem constants: bases [1,4,136,200] f32, box_feat [N,789] f32
// (col0 = image idx, 1:5 = box, 5: = 4*14*14 coeffs), out [N,544,800] f32.
#define OUTD 56
#define COD  14
#define BH   136
#define BW   200
#define IMGH 544
#define IMGW 800
#define BB   4
#define BFS  789   // 5 + 4*14*14
#define RPB  16    // rows per paste block (544 = 34 * 16)

// ---------------------------------------------------------------------------
// K1: build N 56x56 sigmoid masks into workspace. ONE THREAD PER PIXEL
// (grid = 13 x N). Unchanged from previous round — it is not the bottleneck
// (~333k light threads, all inputs L2-resident).
// ---------------------------------------------------------------------------
__global__ __launch_bounds__(256) void mask_kernel(
    const float* __restrict__ bases,
    const float* __restrict__ box_feat,
    float* __restrict__ masks) {
  const int n = blockIdx.y;
  const int p = blockIdx.x * 256 + threadIdx.x;
  if (p >= OUTD * OUTD) return;
  const int y = p / OUTD;
  const int x = p - y * OUTD;

  const float* bf = box_feat + (size_t)n * BFS;
  const int bidx = (int)bf[0];
  const float x0 = bf[1], y0 = bf[2], x1 = bf[3], y1 = bf[4];
  const float sx0 = x0 * 0.25f - 0.5f;
  const float sy0 = y0 * 0.25f - 0.5f;
  const float bwv = (x1 - x0) * 0.25f * (1.0f / OUTD);
  const float bhv = (y1 - y0) * 0.25f * (1.0f / OUTD);
  const float* feat = bases + (size_t)bidx * BB * BH * BW;
  const float* top  = bf + 5;

  // ---- roi_align sample (aligned=True, sampling_ratio=1) ----
  const float ysv = sy0 + ((float)y + 0.5f) * bhv;
  const float xsv = sx0 + ((float)x + 0.5f) * bwv;
  const float valid =
      (ysv >= -1.0f && ysv <= (float)BH && xsv >= -1.0f && xsv <= (float)BW)
          ? 1.0f : 0.0f;
  const float yc = fminf(fmaxf(ysv, 0.0f), (float)(BH - 1));
  const float xc = fminf(fmaxf(xsv, 0.0f), (float)(BW - 1));
  int yl = (int)floorf(yc); yl = yl > (BH - 2) ? (BH - 2) : yl;  // yc >= 0
  int xl = (int)floorf(xc); xl = xl > (BW - 2) ? (BW - 2) : xl;
  const float ly = yc - (float)yl, hy = 1.0f - ly;
  const float lx = xc - (float)xl, hx = 1.0f - lx;
  const float w00 = hy * hx, w01 = hy * lx, w10 = ly * hx, w11 = ly * lx;

  // ---- coeff 14->56 bilinear upsample coords (edge clamp) ----
  float cyf = fminf(fmaxf(((float)y + 0.5f) * 0.25f - 0.5f, 0.0f), (float)(COD - 1));
  float cxf = fminf(fmaxf(((float)x + 0.5f) * 0.25f - 0.5f, 0.0f), (float)(COD - 1));
  int cyl = (int)floorf(cyf); cyl = cyl > (COD - 2) ? (COD - 2) : cyl;
  int cxl = (int)floorf(cxf); cxl = cxl > (COD - 2) ? (COD - 2) : cxl;
  const float cly = cyf - (float)cyl, chy = 1.0f - cly;
  const float clx = cxf - (float)cxl, chx = 1.0f - clx;
  const float cw00 = chy * chx, cw01 = chy * clx, cw10 = cly * chx, cw11 = cly * clx;

  float rvals[BB], cvals[BB];
#pragma unroll
  for (int b = 0; b < BB; ++b) {
    const float* fb = feat + b * BH * BW;
    const float r = w00 * fb[yl * BW + xl]       + w01 * fb[yl * BW + xl + 1] +
                    w10 * fb[(yl + 1) * BW + xl] + w11 * fb[(yl + 1) * BW + xl + 1];
    rvals[b] = r * valid;
    const float* tb = top + b * COD * COD;
    cvals[b] = cw00 * tb[cyl * COD + cxl]       + cw01 * tb[cyl * COD + cxl + 1] +
               cw10 * tb[(cyl + 1) * COD + cxl] + cw11 * tb[(cyl + 1) * COD + cxl + 1];
  }

  const float mx = fmaxf(fmaxf(cvals[0], cvals[1]), fmaxf(cvals[2], cvals[3]));
  float e[BB], s = 0.0f;
#pragma unroll
  for (int b = 0; b < BB; ++b) { e[b] = __expf(cvals[b] - mx); s += e[b]; }
  const float inv = 1.0f / s;
  float dot = 0.0f;
#pragma unroll
  for (int b = 0; b < BB; ++b) dot += rvals[b] * (e[b] * inv);
  masks[(size_t)n * (OUTD * OUTD) + p] = 1.0f / (1.0f + __expf(-dot));
}

// ---------------------------------------------------------------------------
// K2: paste. One block per (16-row band, roi): 3,400 blocks instead of
// 54,400. Thread = one float4 column; per-column x-weights computed ONCE and
// reused across the 16 rows. Row-validity branch is wave-uniform. No LDS /
// no __syncthreads — mask-row gathers (valid rows only, ~23%) hit L1/L2
// (masks = 1.25 MB total; a mask row = 224 B). Zero rows degenerate into a
// pure coalesced float4 store stream (the fill-kernel pattern, 6.6 TB/s).
// NOTE: x-indices are clamped to [0,55] on BOTH sides because loads now
// execute under zeroed weights instead of being branched away.
// ---------------------------------------------------------------------------
__global__ __launch_bounds__(256) void paste_kernel(
    const float* __restrict__ masks,
    const float* __restrict__ box_feat,
    float4* __restrict__ out) {
  const int n  = blockIdx.y;
  const int h0 = blockIdx.x * RPB;
  const int tid = threadIdx.x;
  const bool active = tid < (IMGW / 4);

  const float* bf = box_feat + (size_t)n * BFS;
  const float x0 = bf[1], y0 = bf[2], x1 = bf[3], y1 = bf[4];

  const float invw = (float)OUTD / (x1 - x0);
  const float cx = (0.5f - x0) * invw - 0.5f;   // fx(q) = q*invw + cx
  const float invh = (float)OUTD / (y1 - y0);
  const float cy = (0.5f - y0) * invh - 0.5f;   // fy(h) = h*invh + cy

  // ---- per-column bilinear x setup, reused for all RPB rows ----
  int   xls[4], xhs[4];
  float wx0[4], wx1[4];
#pragma unroll
  for (int i = 0; i < 4; ++i) {
    const float q  = (float)(tid * 4 + i);
    const float fx = fmaf(q, invw, cx);
    const bool vx = (fx > -1.0f && fx < (float)OUTD);
    const int xl = (int)floorf(fx);
    float w1 = fx - (float)xl;
    float w0 = 1.0f - w1;
    if (xl < 0)            w0 = 0.0f;
    if (xl + 1 > OUTD - 1) w1 = 0.0f;
    int lo = xl     < 0        ? 0        : xl;
    lo     = lo     > OUTD - 1 ? OUTD - 1 : lo;      // clamp BOTH sides
    int hi = xl + 1 < 0        ? 0        : xl + 1;
    hi     = hi     > OUTD - 1 ? OUTD - 1 : hi;
    xls[i] = lo;
    xhs[i] = hi;
    wx0[i] = vx ? w0 : 0.0f;
    wx1[i] = vx ? w1 : 0.0f;
  }

  const float* mbase = masks + (size_t)n * (OUTD * OUTD);
  float4* orow = out + ((size_t)n * IMGH + h0) * (IMGW / 4) + tid;

  for (int r = 0; r < RPB; ++r) {
    const int h = h0 + r;
    const float fy = fmaf((float)h, invh, cy);
    float4 v = make_float4(0.f, 0.f, 0.f, 0.f);
    if (fy > -1.0f && fy < (float)OUTD) {        // wave-uniform
      const int ml = (int)floorf(fy);            // -1 .. 55
      float wy1 = fy - (float)ml;
      float wy0 = 1.0f - wy1;
      const int r0 = ml < 0 ? 0 : ml;
      const int r1 = (ml + 1 > OUTD - 1) ? (OUTD - 1) : (ml + 1);
      if (ml < 0)            wy0 = 0.0f;
      if (ml + 1 > OUTD - 1) wy1 = 0.0f;
      const float* m0 = mbase + r0 * OUTD;
      const float* m1 = mbase + r1 * OUTD;
      float res[4];
#pragma unroll
      for (int i = 0; i < 4; ++i) {
        res[i] = wy0 * (wx0[i] * m0[xls[i]] + wx1[i] * m0[xhs[i]]) +
                 wy1 * (wx0[i] * m1[xls[i]] + wx1[i] * m1[xhs[i]]);
      }
      v = make_float4(res[0], res[1], res[2], res[3]);
    }
    if (active) orow[(size_t)r * (IMGW / 4)] = v;
  }
}

extern "C" void kernel_launch(void* const* d_in, const int* in_sizes, int n_in,
                              void* d_out, int out_size, void* d_ws, size_t ws_size,
                              hipStream_t stream) {
  const float* bases    = (const float*)d_in[0];
  const float* box_feat = (const float*)d_in[1];
  const int N = in_sizes[1] / BFS;

  float* masks = (float*)d_ws;  // N*56*56 floats = 1.25 MB for N=100

  dim3 g1((OUTD * OUTD + 255) / 256, N);
  mask_kernel<<<g1, 256, 0, stream>>>(bases, box_feat, masks);

  dim3 g2(IMGH / RPB, N);
  paste_kernel<<<g2, 256, 0, stream>>>(masks, box_feat, (float4*)d_out);
}